// Round 1
// baseline (23811.449 us; speedup 1.0000x reference)
//
#include <hip/hip_runtime.h>

// ---------------------------------------------------------------------------
// FastKAN ConvNet baseline (fp32, correctness-first).
// Layer: p = unfold3x3(x) [N, C*9] (c*9 + ky*3 + kx ordering, zero pad)
//        pn = LN(p)*ln_w + ln_b ; rbf[i,g] = exp(-((pn_i - grid_g)/denom)^2)
//        out = rbf @ Ws^T + silu(p) @ Wb^T + bb   -> [B, OUT, H, W]
// then BN(batch stats) -> ReLU -> MaxPool2x2.
// ---------------------------------------------------------------------------

template<int IN, int OUT, int PPB>
__launch_bounds__(256)
__global__ void fastkan_conv(const float* __restrict__ x, int C, int H, int W,
                             const float* __restrict__ ln_w, const float* __restrict__ ln_b,
                             const float* __restrict__ Wb, const float* __restrict__ bb,
                             const float* __restrict__ Ws,
                             float* __restrict__ out)
{
    extern __shared__ float smem[];
    float* p_s   = smem;             // [PPB][IN]   raw patch, later silu(p)
    float* rbf_s = smem + PPB * IN;  // [PPB][IN*8]
    __shared__ float red_s[4], red2_s[4];
    __shared__ float s_mean[PPB], s_istd[PPB];

    const int tid = threadIdx.x;
    const int HW  = H * W;
    const int base_n = blockIdx.x * PPB;

    // ---- load patches into LDS ----
    for (int pp = 0; pp < PPB; ++pp) {
        int n  = base_n + pp;
        int b  = n / HW; int hw = n % HW;
        int hh = hw / W; int ww = hw % W;
        const float* xb = x + (long)b * C * HW;
        for (int i = tid; i < IN; i += 256) {
            int ch = i / 9, r = i % 9;
            int y  = hh + r / 3 - 1;
            int xx = ww + r % 3 - 1;
            float v = 0.f;
            if (y >= 0 && y < H && xx >= 0 && xx < W)
                v = xb[(ch * H + y) * W + xx];
            p_s[pp * IN + i] = v;
        }
    }
    __syncthreads();

    // ---- LayerNorm stats per pixel ----
    for (int pp = 0; pp < PPB; ++pp) {
        float s = 0.f, s2 = 0.f;
        for (int i = tid; i < IN; i += 256) {
            float v = p_s[pp * IN + i];
            s += v; s2 += v * v;
        }
        for (int off = 32; off > 0; off >>= 1) {
            s  += __shfl_down(s,  off, 64);
            s2 += __shfl_down(s2, off, 64);
        }
        int lane = tid & 63, wid = tid >> 6;
        if (lane == 0) { red_s[wid] = s; red2_s[wid] = s2; }
        __syncthreads();
        if (tid == 0) {
            float ts  = red_s[0] + red_s[1] + red_s[2] + red_s[3];
            float ts2 = red2_s[0] + red2_s[1] + red2_s[2] + red2_s[3];
            float mean = ts / IN;
            float var  = ts2 / IN - mean * mean;
            s_mean[pp] = mean;
            s_istd[pp] = rsqrtf(var + 1e-5f);
        }
        __syncthreads();
    }

    // ---- transform: pn -> rbf basis; p -> silu(p) in place ----
    for (int idx = tid; idx < PPB * IN; idx += 256) {
        int pp = idx / IN, i = idx % IN;
        float v  = p_s[idx];
        float pn = (v - s_mean[pp]) * s_istd[pp] * ln_w[i] + ln_b[i];
        #pragma unroll
        for (int g = 0; g < 8; ++g) {
            float t = (pn - (-2.f + g * (4.f / 7.f))) * 1.75f;  // /DENOM, DENOM=4/7
            rbf_s[(pp * IN + i) * 8 + g] = __expf(-t * t);
        }
        p_s[idx] = v / (1.f + __expf(-v));  // silu
    }
    __syncthreads();

    // ---- dot products: thread t -> (pixel pp, output o) ----
    {
        int pp = tid / OUT, o = tid % OUT;
        int n  = base_n + pp;
        int b  = n / HW; int hw = n % HW;
        int hh = hw / W; int ww = hw % W;

        const float4* wsr = (const float4*)(Ws + (long)o * IN * 8);
        const float4* rb  = (const float4*)(rbf_s + pp * IN * 8);
        float acc = 0.f;
        for (int k = 0; k < IN * 2; ++k) {  // IN*8 / 4
            float4 a = rb[k], w = wsr[k];
            acc += a.x * w.x + a.y * w.y + a.z * w.z + a.w * w.w;
        }
        const float4* wbr = (const float4*)(Wb + (long)o * IN);
        const float4* sp  = (const float4*)(p_s + pp * IN);
        float acc2 = 0.f;
        for (int k = 0; k < IN / 4; ++k) {
            float4 a = sp[k], w = wbr[k];
            acc2 += a.x * w.x + a.y * w.y + a.z * w.z + a.w * w.w;
        }
        out[(long)(b * OUT + o) * HW + hh * W + ww] = acc + acc2 + bb[o];
    }
}

__launch_bounds__(256)
__global__ void bn_stats(const float* __restrict__ h, int C, int HW, int B,
                         float* __restrict__ sums)
{
    int c = blockIdx.y;
    int total = B * HW;
    float s = 0.f, s2 = 0.f;
    for (int idx = blockIdx.x * 256 + threadIdx.x; idx < total; idx += 256 * gridDim.x) {
        int b = idx / HW, r = idx % HW;
        float v = h[((long)b * C + c) * HW + r];
        s += v; s2 += v * v;
    }
    for (int off = 32; off > 0; off >>= 1) {
        s  += __shfl_down(s,  off, 64);
        s2 += __shfl_down(s2, off, 64);
    }
    __shared__ float rs[4], rs2[4];
    int lane = threadIdx.x & 63, wid = threadIdx.x >> 6;
    if (lane == 0) { rs[wid] = s; rs2[wid] = s2; }
    __syncthreads();
    if (threadIdx.x == 0) {
        atomicAdd(&sums[c],     rs[0] + rs[1] + rs[2] + rs[3]);
        atomicAdd(&sums[C + c], rs2[0] + rs2[1] + rs2[2] + rs2[3]);
    }
}

__launch_bounds__(256)
__global__ void bn_relu_pool(const float* __restrict__ h, const float* __restrict__ sums,
                             const float* __restrict__ gamma, const float* __restrict__ beta,
                             float* __restrict__ out, int B, int C, int H, int W)
{
    int Ho = H / 2, Wo = W / 2;
    long total = (long)B * C * Ho * Wo;
    long idx = (long)blockIdx.x * 256 + threadIdx.x;
    if (idx >= total) return;
    int pw = idx % Wo; long t = idx / Wo;
    int ph = t % Ho; t /= Ho;
    int c = t % C; int b = (int)(t / C);

    float M = (float)B * H * W;
    float mean = sums[c] / M;
    float var  = sums[C + c] / M - mean * mean;
    float scale = gamma[c] * rsqrtf(var + 1e-5f);
    float shift = beta[c] - mean * scale;

    const float* hp = h + ((long)b * C + c) * H * W;
    float m = 0.f;  // post-relu values are >= 0
    #pragma unroll
    for (int i = 0; i < 2; ++i)
        #pragma unroll
        for (int j = 0; j < 2; ++j) {
            float v = hp[(2 * ph + i) * W + 2 * pw + j] * scale + shift;
            m = fmaxf(m, v);
        }
    out[idx] = m;
}

extern "C" void kernel_launch(void* const* d_in, const int* in_sizes, int n_in,
                              void* d_out, int out_size, void* d_ws, size_t ws_size,
                              hipStream_t stream) {
    const float* x = (const float*)d_in[0];
    // per-layer params: ln_w, ln_b, Wb, bb, Ws, g, be at 1 + 7*(i-1) ...
    const float* ln_w1 = (const float*)d_in[1];  const float* ln_b1 = (const float*)d_in[2];
    const float* Wb1   = (const float*)d_in[3];  const float* bb1   = (const float*)d_in[4];
    const float* Ws1   = (const float*)d_in[5];  const float* g1    = (const float*)d_in[6];
    const float* be1   = (const float*)d_in[7];
    const float* ln_w2 = (const float*)d_in[8];  const float* ln_b2 = (const float*)d_in[9];
    const float* Wb2   = (const float*)d_in[10]; const float* bb2   = (const float*)d_in[11];
    const float* Ws2   = (const float*)d_in[12]; const float* g2    = (const float*)d_in[13];
    const float* be2   = (const float*)d_in[14];
    const float* ln_w3 = (const float*)d_in[15]; const float* ln_b3 = (const float*)d_in[16];
    const float* Wb3   = (const float*)d_in[17]; const float* bb3   = (const float*)d_in[18];
    const float* Ws3   = (const float*)d_in[19]; const float* g3    = (const float*)d_in[20];
    const float* be3   = (const float*)d_in[21];

    const int B = 32;
    char* ws = (char*)d_ws;
    float* convbuf = (float*)ws;                          // 33,554,432 B max
    float* poolbuf = (float*)(ws + 33554432);             //  8,388,608 B max (reused)
    float* stats1  = (float*)(ws + 33554432 + 8388608);   // 2048 B each
    float* stats2  = (float*)((char*)stats1 + 2048);
    float* stats3  = (float*)((char*)stats2 + 2048);

    hipMemsetAsync(stats1, 0, 6144, stream);

    // ---------------- layer 1: Cin=16, IN=144, OUT=64, H=W=64 ----------------
    {
        const int Cc = 16, H = 64, W = 64, IN = 144, OUT = 64, PPB = 4;
        int nblk = B * H * W / PPB;  // 32768
        size_t smem = (size_t)PPB * IN * 9 * 4;
        fastkan_conv<IN, OUT, PPB><<<nblk, 256, smem, stream>>>(
            x, Cc, H, W, ln_w1, ln_b1, Wb1, bb1, Ws1, convbuf);
        bn_stats<<<dim3(64, OUT), 256, 0, stream>>>(convbuf, OUT, H * W, B, stats1);
        long tot = (long)B * OUT * (H / 2) * (W / 2);
        bn_relu_pool<<<(tot + 255) / 256, 256, 0, stream>>>(
            convbuf, stats1, g1, be1, poolbuf, B, OUT, H, W);
    }
    // ---------------- layer 2: Cin=64, IN=576, OUT=128, H=W=32 ---------------
    {
        const int Cc = 64, H = 32, W = 32, IN = 576, OUT = 128, PPB = 2;
        int nblk = B * H * W / PPB;  // 16384
        size_t smem = (size_t)PPB * IN * 9 * 4;
        fastkan_conv<IN, OUT, PPB><<<nblk, 256, smem, stream>>>(
            poolbuf, Cc, H, W, ln_w2, ln_b2, Wb2, bb2, Ws2, convbuf);
        bn_stats<<<dim3(16, OUT), 256, 0, stream>>>(convbuf, OUT, H * W, B, stats2);
        long tot = (long)B * OUT * (H / 2) * (W / 2);
        bn_relu_pool<<<(tot + 255) / 256, 256, 0, stream>>>(
            convbuf, stats2, g2, be2, poolbuf, B, OUT, H, W);
    }
    // ---------------- layer 3: Cin=128, IN=1152, OUT=256, H=W=16 -------------
    {
        const int Cc = 128, H = 16, W = 16, IN = 1152, OUT = 256, PPB = 1;
        int nblk = B * H * W / PPB;  // 8192
        size_t smem = (size_t)PPB * IN * 9 * 4;
        fastkan_conv<IN, OUT, PPB><<<nblk, 256, smem, stream>>>(
            poolbuf, Cc, H, W, ln_w3, ln_b3, Wb3, bb3, Ws3, convbuf);
        bn_stats<<<dim3(8, OUT), 256, 0, stream>>>(convbuf, OUT, H * W, B, stats3);
        long tot = (long)B * OUT * (H / 2) * (W / 2);  // 524288 == out_size
        bn_relu_pool<<<(tot + 255) / 256, 256, 0, stream>>>(
            convbuf, stats3, g3, be3, (float*)d_out, B, OUT, H, W);
    }
}

// Round 2
// 1743.624 us; speedup vs baseline: 13.6563x; 13.6563x over previous
//
#include <hip/hip_runtime.h>

typedef _Float16 half_t;
typedef __attribute__((ext_vector_type(8))) _Float16 half8;
typedef __attribute__((ext_vector_type(4))) float floatx4;

// ---------------------------------------------------------------------------
// FastKAN layer as one fused fp16-MFMA GEMM:
//   C[pix][o] = sum_k A[pix][k] * Wt[o][k],  k = i*9 + j
//   j<8 : A = exp(-(((p-mu)*istd*lnw+lnb) - grid_j)^2 * 1.75^2),  Wt = Ws[o][i*8+j]
//   j==8: A = silu(p),                                           Wt = Wb[o][i]
// A tile generated on the fly in LDS (patch gather + LN using precomputed
// per-pixel mean/istd). Then BN(batch stats)+ReLU+MaxPool as before.
// ---------------------------------------------------------------------------

// ---- per-pixel LayerNorm stats (mean, 1/std over the C*9 patch) ----
template<int C, int H, int W>
__global__ __launch_bounds__(256)
void ln_stats(const float* __restrict__ x, float* __restrict__ mv,
              float* __restrict__ iv)
{
    const int HW = H * W, IN = C * 9;
    int pix = blockIdx.x * 256 + threadIdx.x;
    int b = pix / HW, hw = pix % HW, h = hw / W, w = hw % W;
    const float* xb = x + (long)b * C * HW;
    float s = 0.f, s2 = 0.f;
    for (int ch = 0; ch < C; ++ch) {
        const float* xc = xb + ch * HW;
        #pragma unroll
        for (int ry = 0; ry < 3; ++ry) {
            int y = h + ry - 1;
            if (y < 0 || y >= H) continue;
            #pragma unroll
            for (int rx = 0; rx < 3; ++rx) {
                int xx = w + rx - 1;
                if (xx < 0 || xx >= W) continue;
                float v = xc[y * W + xx];
                s += v; s2 += v * v;
            }
        }
    }
    float mean = s / IN;                    // zero-pad contributes 0 to sums
    float var  = s2 / IN - mean * mean;     // biased var (matches jnp.var)
    mv[pix] = mean;
    iv[pix] = rsqrtf(var + 1e-5f);
}

// ---- fp32 weights -> fp16, interleaved [OUT][KPAD], k = i*9+j ordering ----
template<int IN, int OUT, int KPAD>
__global__ __launch_bounds__(256)
void conv_w(const float* __restrict__ Ws, const float* __restrict__ Wb,
            half_t* __restrict__ Wt)
{
    int idx = blockIdx.x * 256 + threadIdx.x;
    if (idx >= OUT * KPAD) return;
    int o = idx / KPAD, k = idx - o * KPAD;
    float v = 0.f;
    if (k < IN * 9) {
        int i = k / 9, j = k - i * 9;
        v = (j < 8) ? Ws[(long)o * IN * 8 + i * 8 + j] : Wb[(long)o * IN + i];
    }
    Wt[idx] = (half_t)v;
}

// ---- fused activation-gen + MFMA GEMM; block = 64 pixels x 64 outputs ----
template<int C, int H, int W, int OUT>
__global__ __launch_bounds__(256)
void kan_gemm(const float* __restrict__ x,
              const float* __restrict__ lnw, const float* __restrict__ lnb,
              const half_t* __restrict__ Wt, const float* __restrict__ bb,
              const float* __restrict__ mv, const float* __restrict__ iv,
              float* __restrict__ out)
{
    const int HW = H * W, IN = C * 9, K = IN * 9;
    const int KPAD = (K + 63) & ~63;

    __shared__ half_t As[64][72];   // 64 pixels x 64 k (stride 72: 16B rows)
    __shared__ half_t Bs[64][72];   // 64 outputs x 64 k
    __shared__ float  lw[IN], lb[IN];

    const int tid = threadIdx.x;
    for (int i = tid; i < IN; i += 256) { lw[i] = lnw[i]; lb[i] = lnb[i]; }

    // staging role: thread -> (row 0..63, quarter 0..3 -> 16 k-slots)
    const int row = tid >> 2;
    const int quarter = tid & 3;
    const int pix = blockIdx.x * 64 + row;
    const int b = pix / HW, hw = pix % HW, h = hw / W, w = hw % W;
    const float mean = mv[pix], istd = iv[pix];
    const float* xb = x + (long)b * C * HW;
    const half_t* wrow = Wt + (long)(blockIdx.y * 64 + row) * KPAD + quarter * 16;

    // mfma role: 4 waves in 2x2 over the 64x64 tile, each wave 32x32
    const int wv = tid >> 6, lane = tid & 63;
    const int wm = wv >> 1, wn = wv & 1;
    const int lr = lane & 15, lq = lane >> 4;

    floatx4 acc[2][2] = {};

    for (int k0 = 0; k0 < KPAD; k0 += 64) {
        __syncthreads();   // prev-iter MFMA reads done; lw/lb visible (iter 0)

        // stage weights (coalesced 16B loads)
        const uint4* wsrc = (const uint4*)(wrow + k0);
        *(uint4*)&Bs[row][quarter * 16]     = wsrc[0];
        *(uint4*)&Bs[row][quarter * 16 + 8] = wsrc[1];

        // stage activations: compute 16 A elements for (pixel=row)
        #pragma unroll
        for (int hf = 0; hf < 2; ++hf) {
            half8 tv;
            #pragma unroll
            for (int kk = 0; kk < 8; ++kk) {
                int k = k0 + quarter * 16 + hf * 8 + kk;
                float a = 0.f;
                if (k < K) {
                    int i = k / 9, j = k - i * 9;
                    int ch = i / 9, r = i - ch * 9;
                    int ry = r / 3, rx = r - ry * 3;
                    int y = h + ry - 1, xx = w + rx - 1;
                    float v = 0.f;
                    if (y >= 0 && y < H && xx >= 0 && xx < W)
                        v = xb[ch * HW + y * W + xx];
                    if (j < 8) {
                        float pn = (v - mean) * istd * lw[i] + lb[i];
                        float t = (pn - (-2.f + j * (4.f / 7.f))) * 1.75f;
                        a = __expf(-t * t);
                    } else {
                        a = v / (1.f + __expf(-v));   // silu
                    }
                }
                tv[kk] = (half_t)a;
            }
            *(half8*)&As[row][quarter * 16 + hf * 8] = tv;
        }
        __syncthreads();

        #pragma unroll
        for (int ks = 0; ks < 2; ++ks) {
            half8 a0 = *(const half8*)&As[wm * 32      + lr][ks * 32 + lq * 8];
            half8 a1 = *(const half8*)&As[wm * 32 + 16 + lr][ks * 32 + lq * 8];
            half8 b0 = *(const half8*)&Bs[wn * 32      + lr][ks * 32 + lq * 8];
            half8 b1 = *(const half8*)&Bs[wn * 32 + 16 + lr][ks * 32 + lq * 8];
            acc[0][0] = __builtin_amdgcn_mfma_f32_16x16x32_f16(a0, b0, acc[0][0], 0, 0, 0);
            acc[0][1] = __builtin_amdgcn_mfma_f32_16x16x32_f16(a0, b1, acc[0][1], 0, 0, 0);
            acc[1][0] = __builtin_amdgcn_mfma_f32_16x16x32_f16(a1, b0, acc[1][0], 0, 0, 0);
            acc[1][1] = __builtin_amdgcn_mfma_f32_16x16x32_f16(a1, b1, acc[1][1], 0, 0, 0);
        }
    }

    // epilogue: D[m][n], m=(lq*4+reg) row of frag, n=lr col of frag
    #pragma unroll
    for (int mf = 0; mf < 2; ++mf)
    #pragma unroll
    for (int nf = 0; nf < 2; ++nf)
    #pragma unroll
    for (int reg = 0; reg < 4; ++reg) {
        int m = wm * 32 + mf * 16 + lq * 4 + reg;
        int n = wn * 32 + nf * 16 + lr;
        int p2 = blockIdx.x * 64 + m;
        int o  = blockIdx.y * 64 + n;
        int b2 = p2 / HW, hw2 = p2 % HW;
        out[((long)b2 * OUT + o) * HW + hw2] = acc[mf][nf][reg] + bb[o];
    }
}

// ---- BatchNorm batch-stats / ReLU / MaxPool2x2 (unchanged from baseline) ----
__launch_bounds__(256)
__global__ void bn_stats(const float* __restrict__ h, int C, int HW, int B,
                         float* __restrict__ sums)
{
    int c = blockIdx.y;
    int total = B * HW;
    float s = 0.f, s2 = 0.f;
    for (int idx = blockIdx.x * 256 + threadIdx.x; idx < total; idx += 256 * gridDim.x) {
        int b = idx / HW, r = idx % HW;
        float v = h[((long)b * C + c) * HW + r];
        s += v; s2 += v * v;
    }
    for (int off = 32; off > 0; off >>= 1) {
        s  += __shfl_down(s,  off, 64);
        s2 += __shfl_down(s2, off, 64);
    }
    __shared__ float rs[4], rs2[4];
    int lane = threadIdx.x & 63, wid = threadIdx.x >> 6;
    if (lane == 0) { rs[wid] = s; rs2[wid] = s2; }
    __syncthreads();
    if (threadIdx.x == 0) {
        atomicAdd(&sums[c],     rs[0] + rs[1] + rs[2] + rs[3]);
        atomicAdd(&sums[C + c], rs2[0] + rs2[1] + rs2[2] + rs2[3]);
    }
}

__launch_bounds__(256)
__global__ void bn_relu_pool(const float* __restrict__ h, const float* __restrict__ sums,
                             const float* __restrict__ gamma, const float* __restrict__ beta,
                             float* __restrict__ out, int B, int C, int H, int W)
{
    int Ho = H / 2, Wo = W / 2;
    long total = (long)B * C * Ho * Wo;
    long idx = (long)blockIdx.x * 256 + threadIdx.x;
    if (idx >= total) return;
    int pw = idx % Wo; long t = idx / Wo;
    int ph = t % Ho; t /= Ho;
    int c = t % C; int b = (int)(t / C);

    float M = (float)B * H * W;
    float mean = sums[c] / M;
    float var  = sums[C + c] / M - mean * mean;
    float scale = gamma[c] * rsqrtf(var + 1e-5f);
    float shift = beta[c] - mean * scale;

    const float* hp = h + ((long)b * C + c) * H * W;
    float m = 0.f;  // post-relu >= 0
    #pragma unroll
    for (int i = 0; i < 2; ++i)
        #pragma unroll
        for (int j = 0; j < 2; ++j) {
            float v = hp[(2 * ph + i) * W + 2 * pw + j] * scale + shift;
            m = fmaxf(m, v);
        }
    out[idx] = m;
}

extern "C" void kernel_launch(void* const* d_in, const int* in_sizes, int n_in,
                              void* d_out, int out_size, void* d_ws, size_t ws_size,
                              hipStream_t stream) {
    const float* x     = (const float*)d_in[0];
    const float* ln_w1 = (const float*)d_in[1];  const float* ln_b1 = (const float*)d_in[2];
    const float* Wb1   = (const float*)d_in[3];  const float* bb1   = (const float*)d_in[4];
    const float* Ws1   = (const float*)d_in[5];  const float* g1    = (const float*)d_in[6];
    const float* be1   = (const float*)d_in[7];
    const float* ln_w2 = (const float*)d_in[8];  const float* ln_b2 = (const float*)d_in[9];
    const float* Wb2   = (const float*)d_in[10]; const float* bb2   = (const float*)d_in[11];
    const float* Ws2   = (const float*)d_in[12]; const float* g2    = (const float*)d_in[13];
    const float* be2   = (const float*)d_in[14];
    const float* ln_w3 = (const float*)d_in[15]; const float* ln_b3 = (const float*)d_in[16];
    const float* Wb3   = (const float*)d_in[17]; const float* bb3   = (const float*)d_in[18];
    const float* Ws3   = (const float*)d_in[19]; const float* g3    = (const float*)d_in[20];
    const float* be3   = (const float*)d_in[21];

    const int B = 32;
    char* ws = (char*)d_ws;
    float*  convbuf = (float*)(ws + 0);              // 33,554,432
    float*  poolbuf = (float*)(ws + 33554432);       //  8,388,608
    float*  stats1  = (float*)(ws + 41943040);       //  2048 x3
    float*  stats2  = (float*)(ws + 41945088);
    float*  stats3  = (float*)(ws + 41947136);
    float*  meanb   = (float*)(ws + 41949184);       //  524,288
    float*  istdb   = (float*)(ws + 42473472);       //  524,288
    half_t* wt1     = (half_t*)(ws + 42997760);      //  172,032   (64 x 1344)
    half_t* wt2     = (half_t*)(ws + 43169792);      // 1,327,104  (128 x 5184)
    half_t* wt3     = (half_t*)(ws + 44496896);      // 5,308,416  (256 x 10368)

    hipMemsetAsync(stats1, 0, 6144, stream);

    conv_w<144, 64, 1344><<<(64 * 1344 + 255) / 256, 256, 0, stream>>>(Ws1, Wb1, wt1);
    conv_w<576, 128, 5184><<<(128 * 5184 + 255) / 256, 256, 0, stream>>>(Ws2, Wb2, wt2);
    conv_w<1152, 256, 10368><<<(256 * 10368 + 255) / 256, 256, 0, stream>>>(Ws3, Wb3, wt3);

    // ---------------- layer 1: C=16, H=W=64, OUT=64 ----------------
    {
        const int H = 64, W = 64, OUT = 64;
        int npix = B * H * W;                    // 131072
        ln_stats<16, H, W><<<npix / 256, 256, 0, stream>>>(x, meanb, istdb);
        kan_gemm<16, H, W, OUT><<<dim3(npix / 64, OUT / 64), 256, 0, stream>>>(
            x, ln_w1, ln_b1, wt1, bb1, meanb, istdb, convbuf);
        bn_stats<<<dim3(64, OUT), 256, 0, stream>>>(convbuf, OUT, H * W, B, stats1);
        long tot = (long)B * OUT * (H / 2) * (W / 2);
        bn_relu_pool<<<(tot + 255) / 256, 256, 0, stream>>>(
            convbuf, stats1, g1, be1, poolbuf, B, OUT, H, W);
    }
    // ---------------- layer 2: C=64, H=W=32, OUT=128 ---------------
    {
        const int H = 32, W = 32, OUT = 128;
        int npix = B * H * W;                    // 32768
        ln_stats<64, H, W><<<npix / 256, 256, 0, stream>>>(poolbuf, meanb, istdb);
        kan_gemm<64, H, W, OUT><<<dim3(npix / 64, OUT / 64), 256, 0, stream>>>(
            poolbuf, ln_w2, ln_b2, wt2, bb2, meanb, istdb, convbuf);
        bn_stats<<<dim3(16, OUT), 256, 0, stream>>>(convbuf, OUT, H * W, B, stats2);
        long tot = (long)B * OUT * (H / 2) * (W / 2);
        bn_relu_pool<<<(tot + 255) / 256, 256, 0, stream>>>(
            convbuf, stats2, g2, be2, poolbuf, B, OUT, H, W);
    }
    // ---------------- layer 3: C=128, H=W=16, OUT=256 --------------
    {
        const int H = 16, W = 16, OUT = 256;
        int npix = B * H * W;                    // 8192
        ln_stats<128, H, W><<<npix / 256, 256, 0, stream>>>(poolbuf, meanb, istdb);
        kan_gemm<128, H, W, OUT><<<dim3(npix / 64, OUT / 64), 256, 0, stream>>>(
            poolbuf, ln_w3, ln_b3, wt3, bb3, meanb, istdb, convbuf);
        bn_stats<<<dim3(8, OUT), 256, 0, stream>>>(convbuf, OUT, H * W, B, stats3);
        long tot = (long)B * OUT * (H / 2) * (W / 2);  // 524288 == out_size
        bn_relu_pool<<<(tot + 255) / 256, 256, 0, stream>>>(
            convbuf, stats3, g3, be3, (float*)d_out, B, OUT, H, W);
    }
}

// Round 3
// 642.091 us; speedup vs baseline: 37.0842x; 2.7155x over previous
//
#include <hip/hip_runtime.h>

typedef _Float16 half_t;
typedef __attribute__((ext_vector_type(8))) _Float16 half8;
typedef __attribute__((ext_vector_type(4))) float floatx4;

// ---------------------------------------------------------------------------
// Round 3: FastKAN layer = ln_prep (patch gather + LN -> pn, silu fp16)
//          + fused MFMA GEMM with j-major K ordering (k = j*IN + i):
//            j<8 : A[pix][k] = exp(-(((pn-grid_j))*1.75)^2)   (pn preloaded)
//            j==8: A[pix][k] = silu(p)                        (pure copy)
//          Weights repacked to match. Then BN+ReLU+MaxPool.
// ---------------------------------------------------------------------------

// ---- patch gather + LayerNorm -> pn (fp16), silu (fp16), [pix][IN] ----
template<int C, int H, int W>
__global__ __launch_bounds__(256)
void ln_prep(const float* __restrict__ x,
             const float* __restrict__ lnw, const float* __restrict__ lnb,
             half_t* __restrict__ pn, half_t* __restrict__ sp)
{
    const int HW = H * W, IN = C * 9;
    const int NL = (IN + 63) / 64;
    const int wv = threadIdx.x >> 6, lane = threadIdx.x & 63;
    const int pix = blockIdx.x * 4 + wv;
    const int b = pix / HW, hw = pix % HW, h = hw / W, w = hw % W;
    const float* xb = x + (long)b * C * HW;

    float v[NL];
    float s = 0.f, s2 = 0.f;
    #pragma unroll
    for (int t = 0; t < NL; ++t) {
        int i = t * 64 + lane;
        float val = 0.f;
        if (i < IN) {
            int ch = i / 9, r = i - ch * 9;
            int y = h + r / 3 - 1, xx = w + r % 3 - 1;
            if (y >= 0 && y < H && xx >= 0 && xx < W)
                val = xb[ch * HW + y * W + xx];
        }
        v[t] = val; s += val; s2 += val * val;
    }
    #pragma unroll
    for (int off = 32; off > 0; off >>= 1) {
        s  += __shfl_down(s,  off, 64);
        s2 += __shfl_down(s2, off, 64);
    }
    s = __shfl(s, 0, 64); s2 = __shfl(s2, 0, 64);
    float mean = s / IN;
    float istd = rsqrtf(s2 / IN - mean * mean + 1e-5f);

    #pragma unroll
    for (int t = 0; t < NL; ++t) {
        int i = t * 64 + lane;
        if (i < IN) {
            float val = v[t];
            float pnv = (val - mean) * istd * lnw[i] + lnb[i];
            pn[(long)pix * IN + i] = (half_t)pnv;
            sp[(long)pix * IN + i] = (half_t)(val / (1.f + __expf(-val)));
        }
    }
}

// ---- fp32 weights -> fp16 [OUT][KPAD], j-major k = j*IN + i ----
template<int IN, int OUT, int KPAD>
__global__ __launch_bounds__(256)
void conv_w(const float* __restrict__ Ws, const float* __restrict__ Wb,
            half_t* __restrict__ Wt)
{
    int idx = blockIdx.x * 256 + threadIdx.x;
    if (idx >= OUT * KPAD) return;
    int o = idx / KPAD, k = idx - o * KPAD;
    float v = 0.f;
    if (k < IN * 9) {
        int j = k / IN, i = k - j * IN;
        v = (j < 8) ? Ws[(long)o * IN * 8 + i * 8 + j] : Wb[(long)o * IN + i];
    }
    Wt[idx] = (half_t)v;
}

// ---- fused A-gen + MFMA GEMM; block = 64 pixels x 64 outputs ----
template<int IN, int OUT, int HW>
__global__ __launch_bounds__(256)
void kan_gemm(const half_t* __restrict__ pn, const half_t* __restrict__ sp,
              const half_t* __restrict__ Wt, const float* __restrict__ bb,
              float* __restrict__ out)
{
    const int K = IN * 9, KPAD = (K + 63) & ~63;

    __shared__ half_t As[64][72];   // 64 pixels x 64 k
    __shared__ half_t Bs[64][72];   // 64 outputs x 64 k

    const int tid = threadIdx.x;
    const int row = tid >> 2, quarter = tid & 3;
    const int pix = blockIdx.x * 64 + row;
    const half_t* pnrow = pn + (long)pix * IN;
    const half_t* sprow = sp + (long)pix * IN;
    const half_t* wrow = Wt + (long)(blockIdx.y * 64 + row) * KPAD + quarter * 16;

    const int wv = tid >> 6, lane = tid & 63;
    const int wm = wv >> 1, wn = wv & 1;
    const int lr = lane & 15, lq = lane >> 4;

    floatx4 acc[2][2] = {};   // acc[nf][mf]: rows=outputs, cols=pixels

    for (int k0 = 0; k0 < KPAD; k0 += 64) {
        __syncthreads();

        // stage weights
        const uint4* wsrc = (const uint4*)(wrow + k0);
        *(uint4*)&Bs[row][quarter * 16]     = wsrc[0];
        *(uint4*)&Bs[row][quarter * 16 + 8] = wsrc[1];

        // stage activations: chunk of 16 k has uniform j (IN % 16 == 0)
        int cs = k0 + quarter * 16;
        int j = cs / IN;          // compile-time divisor
        int i0 = cs - j * IN;
        if (j < 8) {
            half8 p0 = *(const half8*)(pnrow + i0);
            half8 p1 = *(const half8*)(pnrow + i0 + 8);
            float g = -2.f + j * (4.f / 7.f);
            half8 a0, a1;
            #pragma unroll
            for (int kk = 0; kk < 8; ++kk) {
                float t0 = ((float)p0[kk] - g) * 1.75f;
                a0[kk] = (half_t)__expf(-t0 * t0);
                float t1 = ((float)p1[kk] - g) * 1.75f;
                a1[kk] = (half_t)__expf(-t1 * t1);
            }
            *(half8*)&As[row][quarter * 16]     = a0;
            *(half8*)&As[row][quarter * 16 + 8] = a1;
        } else if (j == 8) {
            *(half8*)&As[row][quarter * 16]     = *(const half8*)(sprow + i0);
            *(half8*)&As[row][quarter * 16 + 8] = *(const half8*)(sprow + i0 + 8);
        } else {                   // K padding
            half8 z = {};
            *(half8*)&As[row][quarter * 16]     = z;
            *(half8*)&As[row][quarter * 16 + 8] = z;
        }
        __syncthreads();

        #pragma unroll
        for (int ks = 0; ks < 2; ++ks) {
            half8 a0 = *(const half8*)&As[wm * 32      + lr][ks * 32 + lq * 8];
            half8 a1 = *(const half8*)&As[wm * 32 + 16 + lr][ks * 32 + lq * 8];
            half8 b0 = *(const half8*)&Bs[wn * 32      + lr][ks * 32 + lq * 8];
            half8 b1 = *(const half8*)&Bs[wn * 32 + 16 + lr][ks * 32 + lq * 8];
            // operands swapped: D rows=outputs, cols=pixels -> coalesced stores
            acc[0][0] = __builtin_amdgcn_mfma_f32_16x16x32_f16(b0, a0, acc[0][0], 0, 0, 0);
            acc[0][1] = __builtin_amdgcn_mfma_f32_16x16x32_f16(b0, a1, acc[0][1], 0, 0, 0);
            acc[1][0] = __builtin_amdgcn_mfma_f32_16x16x32_f16(b1, a0, acc[1][0], 0, 0, 0);
            acc[1][1] = __builtin_amdgcn_mfma_f32_16x16x32_f16(b1, a1, acc[1][1], 0, 0, 0);
        }
    }

    // epilogue: o = row index (lq*4+reg), pixel = col index (lr)
    #pragma unroll
    for (int nf = 0; nf < 2; ++nf)
    #pragma unroll
    for (int mf = 0; mf < 2; ++mf)
    #pragma unroll
    for (int reg = 0; reg < 4; ++reg) {
        int o  = blockIdx.y * 64 + wn * 32 + nf * 16 + lq * 4 + reg;
        int p2 = blockIdx.x * 64 + wm * 32 + mf * 16 + lr;
        int b2 = p2 / HW, hw2 = p2 % HW;
        out[((long)b2 * OUT + o) * HW + hw2] = acc[nf][mf][reg] + bb[o];
    }
}

// ---- BatchNorm batch-stats / ReLU / MaxPool2x2 ----
__launch_bounds__(256)
__global__ void bn_stats(const float* __restrict__ h, int C, int HW, int B,
                         float* __restrict__ sums)
{
    int c = blockIdx.y;
    int total = B * HW;
    float s = 0.f, s2 = 0.f;
    for (int idx = blockIdx.x * 256 + threadIdx.x; idx < total; idx += 256 * gridDim.x) {
        int b = idx / HW, r = idx % HW;
        float v = h[((long)b * C + c) * HW + r];
        s += v; s2 += v * v;
    }
    for (int off = 32; off > 0; off >>= 1) {
        s  += __shfl_down(s,  off, 64);
        s2 += __shfl_down(s2, off, 64);
    }
    __shared__ float rs[4], rs2[4];
    int lane = threadIdx.x & 63, wid = threadIdx.x >> 6;
    if (lane == 0) { rs[wid] = s; rs2[wid] = s2; }
    __syncthreads();
    if (threadIdx.x == 0) {
        atomicAdd(&sums[c],     rs[0] + rs[1] + rs[2] + rs[3]);
        atomicAdd(&sums[C + c], rs2[0] + rs2[1] + rs2[2] + rs2[3]);
    }
}

__launch_bounds__(256)
__global__ void bn_relu_pool(const float* __restrict__ h, const float* __restrict__ sums,
                             const float* __restrict__ gamma, const float* __restrict__ beta,
                             float* __restrict__ out, int B, int C, int H, int W)
{
    int Ho = H / 2, Wo = W / 2;
    long total = (long)B * C * Ho * Wo;
    long idx = (long)blockIdx.x * 256 + threadIdx.x;
    if (idx >= total) return;
    int pw = idx % Wo; long t = idx / Wo;
    int ph = t % Ho; t /= Ho;
    int c = t % C; int b = (int)(t / C);

    float M = (float)B * H * W;
    float mean = sums[c] / M;
    float var  = sums[C + c] / M - mean * mean;
    float scale = gamma[c] * rsqrtf(var + 1e-5f);
    float shift = beta[c] - mean * scale;

    const float* hp = h + ((long)b * C + c) * H * W;
    float m = 0.f;  // post-relu >= 0
    #pragma unroll
    for (int i = 0; i < 2; ++i)
        #pragma unroll
        for (int j = 0; j < 2; ++j) {
            float v = hp[(2 * ph + i) * W + 2 * pw + j] * scale + shift;
            m = fmaxf(m, v);
        }
    out[idx] = m;
}

extern "C" void kernel_launch(void* const* d_in, const int* in_sizes, int n_in,
                              void* d_out, int out_size, void* d_ws, size_t ws_size,
                              hipStream_t stream) {
    const float* x     = (const float*)d_in[0];
    const float* ln_w1 = (const float*)d_in[1];  const float* ln_b1 = (const float*)d_in[2];
    const float* Wb1   = (const float*)d_in[3];  const float* bb1   = (const float*)d_in[4];
    const float* Ws1   = (const float*)d_in[5];  const float* g1    = (const float*)d_in[6];
    const float* be1   = (const float*)d_in[7];
    const float* ln_w2 = (const float*)d_in[8];  const float* ln_b2 = (const float*)d_in[9];
    const float* Wb2   = (const float*)d_in[10]; const float* bb2   = (const float*)d_in[11];
    const float* Ws2   = (const float*)d_in[12]; const float* g2    = (const float*)d_in[13];
    const float* be2   = (const float*)d_in[14];
    const float* ln_w3 = (const float*)d_in[15]; const float* ln_b3 = (const float*)d_in[16];
    const float* Wb3   = (const float*)d_in[17]; const float* bb3   = (const float*)d_in[18];
    const float* Ws3   = (const float*)d_in[19]; const float* g3    = (const float*)d_in[20];
    const float* be3   = (const float*)d_in[21];

    const int B = 32;
    char* ws = (char*)d_ws;
    float*  convbuf = (float*)(ws + 0);              // 33,554,432
    float*  poolbuf = (float*)(ws + 33554432);       //  8,388,608
    float*  stats1  = (float*)(ws + 41943040);       //  2048 x3
    float*  stats2  = (float*)(ws + 41945088);
    float*  stats3  = (float*)(ws + 41947136);
    half_t* wt1     = (half_t*)(ws + 41949184);      //   172,032  (64 x 1344)
    half_t* wt2     = (half_t*)(ws + 42121216);      // 1,327,104  (128 x 5184)
    half_t* wt3     = (half_t*)(ws + 43448320);      // 5,308,416  (256 x 10368)
    half_t* pnbuf   = (half_t*)(ws + 48756736);      // 37,748,736 (max 131072x144)
    half_t* spbuf   = (half_t*)(ws + 86505472);      // 37,748,736
    // total: 124,254,208 B

    hipMemsetAsync(stats1, 0, 6144, stream);

    conv_w<144, 64, 1344><<<(64 * 1344 + 255) / 256, 256, 0, stream>>>(Ws1, Wb1, wt1);
    conv_w<576, 128, 5184><<<(128 * 5184 + 255) / 256, 256, 0, stream>>>(Ws2, Wb2, wt2);
    conv_w<1152, 256, 10368><<<(256 * 10368 + 255) / 256, 256, 0, stream>>>(Ws3, Wb3, wt3);

    // ---------------- layer 1: C=16, H=W=64, OUT=64 ----------------
    {
        const int H = 64, W = 64, OUT = 64;
        int npix = B * H * W;                    // 131072
        ln_prep<16, H, W><<<npix / 4, 256, 0, stream>>>(x, ln_w1, ln_b1, pnbuf, spbuf);
        kan_gemm<144, OUT, H * W><<<dim3(npix / 64, OUT / 64), 256, 0, stream>>>(
            pnbuf, spbuf, wt1, bb1, convbuf);
        bn_stats<<<dim3(64, OUT), 256, 0, stream>>>(convbuf, OUT, H * W, B, stats1);
        long tot = (long)B * OUT * (H / 2) * (W / 2);
        bn_relu_pool<<<(tot + 255) / 256, 256, 0, stream>>>(
            convbuf, stats1, g1, be1, poolbuf, B, OUT, H, W);
    }
    // ---------------- layer 2: C=64, H=W=32, OUT=128 ---------------
    {
        const int H = 32, W = 32, OUT = 128;
        int npix = B * H * W;                    // 32768
        ln_prep<64, H, W><<<npix / 4, 256, 0, stream>>>(poolbuf, ln_w2, ln_b2, pnbuf, spbuf);
        kan_gemm<576, OUT, H * W><<<dim3(npix / 64, OUT / 64), 256, 0, stream>>>(
            pnbuf, spbuf, wt2, bb2, convbuf);
        bn_stats<<<dim3(16, OUT), 256, 0, stream>>>(convbuf, OUT, H * W, B, stats2);
        long tot = (long)B * OUT * (H / 2) * (W / 2);
        bn_relu_pool<<<(tot + 255) / 256, 256, 0, stream>>>(
            convbuf, stats2, g2, be2, poolbuf, B, OUT, H, W);
    }
    // ---------------- layer 3: C=128, H=W=16, OUT=256 --------------
    {
        const int H = 16, W = 16, OUT = 256;
        int npix = B * H * W;                    // 8192
        ln_prep<128, H, W><<<npix / 4, 256, 0, stream>>>(poolbuf, ln_w3, ln_b3, pnbuf, spbuf);
        kan_gemm<1152, OUT, H * W><<<dim3(npix / 64, OUT / 64), 256, 0, stream>>>(
            pnbuf, spbuf, wt3, bb3, convbuf);
        bn_stats<<<dim3(8, OUT), 256, 0, stream>>>(convbuf, OUT, H * W, B, stats3);
        long tot = (long)B * OUT * (H / 2) * (W / 2);  // 524288 == out_size
        bn_relu_pool<<<(tot + 255) / 256, 256, 0, stream>>>(
            convbuf, stats3, g3, be3, (float*)d_out, B, OUT, H, W);
    }
}

// Round 4
// 548.278 us; speedup vs baseline: 43.4295x; 1.1711x over previous
//
#include <hip/hip_runtime.h>

typedef _Float16 half_t;
typedef __attribute__((ext_vector_type(8))) _Float16 half8;
typedef __attribute__((ext_vector_type(4))) float floatx4;

// ---------------------------------------------------------------------------
// Round 4: fused FastKAN GEMM with NB n-tiles/block + split-K + XOR-swizzled
// LDS (conflict-free b128). A[pix][k], k = j*IN + i (j-major):
//   j<8 : exp2(-(pn' - g'_j)^2), pn' = 1.75*sqrt(log2e)*LN(p)  (pre-scaled)
//   j==8: silu(p)
// GEMM partials atomicAdd'd (SPLIT>1); bias bb folded into BN kernels.
// ---------------------------------------------------------------------------

#define RBF_SCALE 2.1019644f   // 1.75 * sqrt(log2(e))

// ---- patch gather + LayerNorm -> pn' (fp16, pre-scaled), silu (fp16) ----
template<int C, int H, int W>
__global__ __launch_bounds__(256)
void ln_prep(const float* __restrict__ x,
             const float* __restrict__ lnw, const float* __restrict__ lnb,
             half_t* __restrict__ pn, half_t* __restrict__ sp)
{
    const int HW = H * W, IN = C * 9;
    const int NL = (IN + 63) / 64;
    const int wv = threadIdx.x >> 6, lane = threadIdx.x & 63;
    const int pix = blockIdx.x * 4 + wv;
    const int b = pix / HW, hw = pix % HW, h = hw / W, w = hw % W;
    const float* xb = x + (long)b * C * HW;

    float v[NL];
    float s = 0.f, s2 = 0.f;
    #pragma unroll
    for (int t = 0; t < NL; ++t) {
        int i = t * 64 + lane;
        float val = 0.f;
        if (i < IN) {
            int ch = i / 9, r = i - ch * 9;
            int y = h + r / 3 - 1, xx = w + r % 3 - 1;
            if (y >= 0 && y < H && xx >= 0 && xx < W)
                val = xb[ch * HW + y * W + xx];
        }
        v[t] = val; s += val; s2 += val * val;
    }
    #pragma unroll
    for (int off = 32; off > 0; off >>= 1) {
        s  += __shfl_down(s,  off, 64);
        s2 += __shfl_down(s2, off, 64);
    }
    s = __shfl(s, 0, 64); s2 = __shfl(s2, 0, 64);
    float mean = s / IN;
    float istd = rsqrtf(s2 / IN - mean * mean + 1e-5f);

    #pragma unroll
    for (int t = 0; t < NL; ++t) {
        int i = t * 64 + lane;
        if (i < IN) {
            float val = v[t];
            float pnv = (val - mean) * istd * lnw[i] + lnb[i];
            pn[(long)pix * IN + i] = (half_t)(pnv * RBF_SCALE);
            sp[(long)pix * IN + i] = (half_t)(val / (1.f + __expf(-val)));
        }
    }
}

// ---- fp32 weights -> fp16 [OUT][KPAD], j-major k = j*IN + i ----
template<int IN, int OUT, int KPAD>
__global__ __launch_bounds__(256)
void conv_w(const float* __restrict__ Ws, const float* __restrict__ Wb,
            half_t* __restrict__ Wt)
{
    int idx = blockIdx.x * 256 + threadIdx.x;
    if (idx >= OUT * KPAD) return;
    int o = idx / KPAD, k = idx - o * KPAD;
    float v = 0.f;
    if (k < IN * 9) {
        int j = k / IN, i = k - j * IN;
        v = (j < 8) ? Ws[(long)o * IN * 8 + i * 8 + j] : Wb[(long)o * IN + i];
    }
    Wt[idx] = (half_t)v;
}

// ---- fused A-gen + MFMA GEMM ----
// block: 64 pixels x NB*64 outputs; wave wv: NB*16 outputs x 64 pixels.
// LDS XOR swizzle: 16B unit u stored at u ^ (row & 7), row stride 64 halfs.
template<int IN, int OUT, int HW, int NB, int SPLIT>
__global__ __launch_bounds__(256)
void kan_gemm(const half_t* __restrict__ pn, const half_t* __restrict__ sp,
              const half_t* __restrict__ Wt, float* __restrict__ out)
{
    const int K = IN * 9, KPAD = (K + 63) & ~63, KIT = KPAD / 64;

    __shared__ half_t As[64 * 64];
    __shared__ half_t Bs[NB * 64 * 64];

    const int tid = threadIdx.x;
    const int row = tid >> 2, q = tid & 3;
    const int pix = blockIdx.x * 64 + row;
    const half_t* pnrow = pn + (long)pix * IN;
    const half_t* sprow = sp + (long)pix * IN;
    const int yoff = blockIdx.y * NB * 64;
    const half_t* wbase = Wt + (long)(yoff + row) * KPAD + q * 16;

    const int wv = tid >> 6, lane = tid & 63;
    const int lr = lane & 15, lq = lane >> 4;
    const int u0 = (2 * q) ^ (row & 7);         // swizzled 16B units
    const int u1 = (2 * q + 1) ^ (row & 7);

    floatx4 acc[NB][4] = {};

    const int it0 = (blockIdx.z * KIT) / SPLIT;
    const int it1 = ((blockIdx.z + 1) * KIT) / SPLIT;

    for (int it = it0; it < it1; ++it) {
        const int k0 = it * 64;
        __syncthreads();   // previous MFMA reads done

        // ---- stage B (NB tiles of 64 outputs x 64 k) ----
        #pragma unroll
        for (int nb = 0; nb < NB; ++nb) {
            const uint4* src = (const uint4*)(wbase + (long)nb * 64 * KPAD + k0);
            int r2 = nb * 64 + row;
            *(uint4*)&Bs[r2 * 64 + u0 * 8] = src[0];
            *(uint4*)&Bs[r2 * 64 + u1 * 8] = src[1];
        }

        // ---- stage A: 16 elements, uniform j per 16-chunk (IN % 16 == 0) ----
        {
            int cs = k0 + q * 16;
            int j = cs / IN;
            half8 a0, a1;
            if (j < 8) {
                int i0 = cs - j * IN;
                float gj = RBF_SCALE * (-2.f + j * (4.f / 7.f));
                half8 p0 = *(const half8*)(pnrow + i0);
                half8 p1 = *(const half8*)(pnrow + i0 + 8);
                #pragma unroll
                for (int kk = 0; kk < 8; ++kk) {
                    float v0 = (float)p0[kk] - gj;
                    a0[kk] = (half_t)__builtin_amdgcn_exp2f(-(v0 * v0));
                    float v1 = (float)p1[kk] - gj;
                    a1[kk] = (half_t)__builtin_amdgcn_exp2f(-(v1 * v1));
                }
            } else if (j == 8) {
                int i0 = cs - 8 * IN;
                a0 = *(const half8*)(sprow + i0);
                a1 = *(const half8*)(sprow + i0 + 8);
            } else {
                a0 = half8{}; a1 = half8{};
            }
            *(half8*)&As[row * 64 + u0 * 8] = a0;
            *(half8*)&As[row * 64 + u1 * 8] = a1;
        }
        __syncthreads();

        // ---- MFMA ----
        #pragma unroll
        for (int ks = 0; ks < 2; ++ks) {
            half8 af[4], bf[NB];
            #pragma unroll
            for (int mf = 0; mf < 4; ++mf) {
                int r = mf * 16 + lr;
                af[mf] = *(const half8*)&As[r * 64 + (((ks * 4 + lq) ^ (r & 7)) * 8)];
            }
            #pragma unroll
            for (int nb = 0; nb < NB; ++nb) {
                int r = wv * NB * 16 + nb * 16 + lr;
                bf[nb] = *(const half8*)&Bs[r * 64 + (((ks * 4 + lq) ^ (r & 7)) * 8)];
            }
            #pragma unroll
            for (int nb = 0; nb < NB; ++nb)
                #pragma unroll
                for (int mf = 0; mf < 4; ++mf)
                    acc[nb][mf] = __builtin_amdgcn_mfma_f32_16x16x32_f16(
                        bf[nb], af[mf], acc[nb][mf], 0, 0, 0);
        }
    }

    // ---- epilogue: rows = outputs (lq*4+reg), cols = pixels (lr) ----
    #pragma unroll
    for (int nb = 0; nb < NB; ++nb)
    #pragma unroll
    for (int mf = 0; mf < 4; ++mf)
    #pragma unroll
    for (int reg = 0; reg < 4; ++reg) {
        int o  = yoff + wv * NB * 16 + nb * 16 + lq * 4 + reg;
        int p2 = blockIdx.x * 64 + mf * 16 + lr;
        int b2 = p2 / HW, hw2 = p2 % HW;
        long off = ((long)b2 * OUT + o) * HW + hw2;
        if (SPLIT == 1) out[off] = acc[nb][mf][reg];
        else            atomicAdd(&out[off], acc[nb][mf][reg]);
    }
}

// ---- BatchNorm batch-stats (bias folded in) ----
__launch_bounds__(256)
__global__ void bn_stats(const float* __restrict__ h, const float* __restrict__ bias,
                         int C, int HW, int B, float* __restrict__ sums)
{
    int c = blockIdx.y;
    float bbc = bias[c];
    int total = B * HW;
    float s = 0.f, s2 = 0.f;
    for (int idx = blockIdx.x * 256 + threadIdx.x; idx < total; idx += 256 * gridDim.x) {
        int b = idx / HW, r = idx % HW;
        float v = h[((long)b * C + c) * HW + r] + bbc;
        s += v; s2 += v * v;
    }
    for (int off = 32; off > 0; off >>= 1) {
        s  += __shfl_down(s,  off, 64);
        s2 += __shfl_down(s2, off, 64);
    }
    __shared__ float rs[4], rs2[4];
    int lane = threadIdx.x & 63, wid = threadIdx.x >> 6;
    if (lane == 0) { rs[wid] = s; rs2[wid] = s2; }
    __syncthreads();
    if (threadIdx.x == 0) {
        atomicAdd(&sums[c],     rs[0] + rs[1] + rs[2] + rs[3]);
        atomicAdd(&sums[C + c], rs2[0] + rs2[1] + rs2[2] + rs2[3]);
    }
}

__launch_bounds__(256)
__global__ void bn_relu_pool(const float* __restrict__ h, const float* __restrict__ sums,
                             const float* __restrict__ bias,
                             const float* __restrict__ gamma, const float* __restrict__ beta,
                             float* __restrict__ out, int B, int C, int H, int W)
{
    int Ho = H / 2, Wo = W / 2;
    long total = (long)B * C * Ho * Wo;
    long idx = (long)blockIdx.x * 256 + threadIdx.x;
    if (idx >= total) return;
    int pw = idx % Wo; long t = idx / Wo;
    int ph = t % Ho; t /= Ho;
    int c = t % C; int b = (int)(t / C);

    float M = (float)B * H * W;
    float mean = sums[c] / M;
    float var  = sums[C + c] / M - mean * mean;
    float scale = gamma[c] * rsqrtf(var + 1e-5f);
    float shift = beta[c] - mean * scale + bias[c] * scale;  // fold conv bias

    const float* hp = h + ((long)b * C + c) * H * W;
    float m = 0.f;  // post-relu >= 0
    #pragma unroll
    for (int i = 0; i < 2; ++i)
        #pragma unroll
        for (int j = 0; j < 2; ++j) {
            float v = hp[(2 * ph + i) * W + 2 * pw + j] * scale + shift;
            m = fmaxf(m, v);
        }
    out[idx] = m;
}

extern "C" void kernel_launch(void* const* d_in, const int* in_sizes, int n_in,
                              void* d_out, int out_size, void* d_ws, size_t ws_size,
                              hipStream_t stream) {
    const float* x     = (const float*)d_in[0];
    const float* ln_w1 = (const float*)d_in[1];  const float* ln_b1 = (const float*)d_in[2];
    const float* Wb1   = (const float*)d_in[3];  const float* bb1   = (const float*)d_in[4];
    const float* Ws1   = (const float*)d_in[5];  const float* g1    = (const float*)d_in[6];
    const float* be1   = (const float*)d_in[7];
    const float* ln_w2 = (const float*)d_in[8];  const float* ln_b2 = (const float*)d_in[9];
    const float* Wb2   = (const float*)d_in[10]; const float* bb2   = (const float*)d_in[11];
    const float* Ws2   = (const float*)d_in[12]; const float* g2    = (const float*)d_in[13];
    const float* be2   = (const float*)d_in[14];
    const float* ln_w3 = (const float*)d_in[15]; const float* ln_b3 = (const float*)d_in[16];
    const float* Wb3   = (const float*)d_in[17]; const float* bb3   = (const float*)d_in[18];
    const float* Ws3   = (const float*)d_in[19]; const float* g3    = (const float*)d_in[20];
    const float* be3   = (const float*)d_in[21];

    const int B = 32;
    char* ws = (char*)d_ws;
    float*  convbuf = (float*)(ws + 0);              // 33,554,432
    float*  poolbuf = (float*)(ws + 33554432);       //  8,388,608
    float*  stats1  = (float*)(ws + 41943040);       //  2048 x3
    float*  stats2  = (float*)(ws + 41945088);
    float*  stats3  = (float*)(ws + 41947136);
    half_t* wt1     = (half_t*)(ws + 41949184);      //   172,032  (64 x 1344)
    half_t* wt2     = (half_t*)(ws + 42121216);      // 1,327,104  (128 x 5184)
    half_t* wt3     = (half_t*)(ws + 43448320);      // 5,308,416  (256 x 10368)
    half_t* pnbuf   = (half_t*)(ws + 48756736);      // 37,748,736 (max 131072x144)
    half_t* spbuf   = (half_t*)(ws + 86505472);      // 37,748,736
    // total: 124,254,208 B

    hipMemsetAsync(stats1, 0, 6144, stream);

    conv_w<144, 64, 1344><<<(64 * 1344 + 255) / 256, 256, 0, stream>>>(Ws1, Wb1, wt1);
    conv_w<576, 128, 5184><<<(128 * 5184 + 255) / 256, 256, 0, stream>>>(Ws2, Wb2, wt2);
    conv_w<1152, 256, 10368><<<(256 * 10368 + 255) / 256, 256, 0, stream>>>(Ws3, Wb3, wt3);

    // ---------------- layer 1: C=16, H=W=64, OUT=64, NB=1, SPLIT=1 ----------
    {
        const int H = 64, W = 64, OUT = 64;
        int npix = B * H * W;                    // 131072
        ln_prep<16, H, W><<<npix / 4, 256, 0, stream>>>(x, ln_w1, ln_b1, pnbuf, spbuf);
        kan_gemm<144, OUT, H * W, 1, 1><<<dim3(npix / 64, 1, 1), 256, 0, stream>>>(
            pnbuf, spbuf, wt1, convbuf);
        bn_stats<<<dim3(64, OUT), 256, 0, stream>>>(convbuf, bb1, OUT, H * W, B, stats1);
        long tot = (long)B * OUT * (H / 2) * (W / 2);
        bn_relu_pool<<<(tot + 255) / 256, 256, 0, stream>>>(
            convbuf, stats1, bb1, g1, be1, poolbuf, B, OUT, H, W);
    }
    // ---------------- layer 2: C=64, H=W=32, OUT=128, NB=2, SPLIT=2 ---------
    {
        const int H = 32, W = 32, OUT = 128;
        int npix = B * H * W;                    // 32768
        ln_prep<64, H, W><<<npix / 4, 256, 0, stream>>>(poolbuf, ln_w2, ln_b2, pnbuf, spbuf);
        hipMemsetAsync(convbuf, 0, (long)npix * OUT * 4, stream);   // 16.8 MB
        kan_gemm<576, OUT, H * W, 2, 2><<<dim3(npix / 64, 1, 2), 256, 0, stream>>>(
            pnbuf, spbuf, wt2, convbuf);
        bn_stats<<<dim3(16, OUT), 256, 0, stream>>>(convbuf, bb2, OUT, H * W, B, stats2);
        long tot = (long)B * OUT * (H / 2) * (W / 2);
        bn_relu_pool<<<(tot + 255) / 256, 256, 0, stream>>>(
            convbuf, stats2, bb2, g2, be2, poolbuf, B, OUT, H, W);
    }
    // ---------------- layer 3: C=128, H=W=16, OUT=256, NB=4, SPLIT=6 --------
    {
        const int H = 16, W = 16, OUT = 256;
        int npix = B * H * W;                    // 8192
        ln_prep<128, H, W><<<npix / 4, 256, 0, stream>>>(poolbuf, ln_w3, ln_b3, pnbuf, spbuf);
        hipMemsetAsync(convbuf, 0, (long)npix * OUT * 4, stream);   // 8.4 MB
        kan_gemm<1152, OUT, H * W, 4, 6><<<dim3(npix / 64, 1, 6), 256, 0, stream>>>(
            pnbuf, spbuf, wt3, convbuf);
        bn_stats<<<dim3(8, OUT), 256, 0, stream>>>(convbuf, bb3, OUT, H * W, B, stats3);
        long tot = (long)B * OUT * (H / 2) * (W / 2);  // 524288 == out_size
        bn_relu_pool<<<(tot + 255) / 256, 256, 0, stream>>>(
            convbuf, stats3, bb3, g3, be3, (float*)d_out, B, OUT, H, W);
    }
}